// Round 9
// baseline (155.635 us; speedup 1.0000x reference)
//
#include <hip/hip_runtime.h>

#define N_NODES 16384
#define N_EDGES 65536

typedef float f32x16 __attribute__((ext_vector_type(16)));
typedef float f32x8  __attribute__((ext_vector_type(8)));

__device__ __forceinline__ float rfl_f(float v) {
    int i = __builtin_amdgcn_readfirstlane(__builtin_bit_cast(int, v));
    return __builtin_bit_cast(float, i);
}

// h1[n,o] = bias1[o] + sum_{i<8} x[n,i] * root1[i,o]
__global__ void k_node1(const float* __restrict__ x, const float* __restrict__ root1,
                        const float* __restrict__ bias1, float* __restrict__ h1) {
    int t = blockIdx.x * blockDim.x + threadIdx.x;   // t in [0, N*64)
    int n = t >> 6, o = t & 63;
    float acc = bias1[o];
#pragma unroll
    for (int i = 0; i < 8; ++i)
        acc = fmaf(x[n * 8 + i], root1[i * 64 + o], acc);
    h1[t] = acc;
}

// layer-1 edge kernel: wave per EDGE-PAIR; 24 weight floats/lane (fits easily)
__global__ __launch_bounds__(256)
void k_edge1(const float* __restrict__ x, const int* __restrict__ ei,
             const float* __restrict__ ea, const float* __restrict__ A1,
             const float* __restrict__ b1, float* __restrict__ h1) {
    int lane = threadIdx.x & 63;
    f32x8 W0, W1, BB;
#pragma unroll
    for (int i = 0; i < 8; ++i) {
        W0[i] = A1[i * 64 + lane];
        W1[i] = A1[512 + i * 64 + lane];
        BB[i] = b1[i * 64 + lane];
    }
    asm volatile("" : "+v"(W0), "+v"(W1), "+v"(BB));

    int wid = blockIdx.x * (blockDim.x >> 6) + (threadIdx.x >> 6);
    int nw = gridDim.x * (blockDim.x >> 6);
#pragma clang loop unroll(disable)
    for (int p = wid; p < N_EDGES / 2; p += nw) {
        int2 srcp = ((const int2*)ei)[p];
        int2 dstp = ((const int2*)(ei + N_EDGES))[p];
        float4 eap = ((const float4*)ea)[p];
        int s0 = __builtin_amdgcn_readfirstlane(srcp.x);
        int s1 = __builtin_amdgcn_readfirstlane(srcp.y);
        int d0 = __builtin_amdgcn_readfirstlane(dstp.x);
        int d1 = __builtin_amdgcn_readfirstlane(dstp.y);
        float ea00 = rfl_f(eap.x), ea01 = rfl_f(eap.y);
        float ea10 = rfl_f(eap.z), ea11 = rfl_f(eap.w);
        const float* xp0 = x + (size_t)s0 * 8;
        const float* xp1 = x + (size_t)s1 * 8;
        f32x8 ha, hb;
        asm volatile("s_load_dwordx8 %0, %2, 0x0\n\t"
                     "s_load_dwordx8 %1, %3, 0x0\n\t"
                     "s_waitcnt lgkmcnt(0)"
                     : "=s"(ha), "=s"(hb) : "s"(xp0), "s"(xp1));
        float acc0 = 0.f, acc1 = 0.f;
#pragma unroll
        for (int i = 0; i < 8; ++i) {
            float wva = fmaxf(fmaf(ea01, W1[i], fmaf(ea00, W0[i], BB[i])), 0.f);
            acc0 = fmaf(ha[i], wva, acc0);
            float wvb = fmaxf(fmaf(ea11, W1[i], fmaf(ea10, W0[i], BB[i])), 0.f);
            acc1 = fmaf(hb[i], wvb, acc1);
        }
        atomicAdd(&h1[(size_t)d0 * 64 + lane], acc0);
        atomicAdd(&h1[(size_t)d1 * 64 + lane], acc1);
    }
}

// out[n,o] = bias2[o] + sum_{i<64} h1[n,i] * root2[i,o]
// wave per node; root2 column (64 floats/lane) held resident via waves_per_eu(4,4)
__global__ __launch_bounds__(256) __attribute__((amdgpu_waves_per_eu(4, 4)))
void k_node2(const float* __restrict__ h1, const float* __restrict__ root2,
             const float* __restrict__ bias2, float* __restrict__ out) {
    int lane = threadIdx.x & 63;
    f32x16 R0, R1, R2, R3;
#pragma unroll
    for (int i = 0; i < 16; ++i) {
        R0[i] = root2[(i)      * 64 + lane];
        R1[i] = root2[(16 + i) * 64 + lane];
        R2[i] = root2[(32 + i) * 64 + lane];
        R3[i] = root2[(48 + i) * 64 + lane];
    }
    asm volatile("" : "+v"(R0), "+v"(R1), "+v"(R2), "+v"(R3));
    float bias = bias2[lane];

    int wid = blockIdx.x * (blockDim.x >> 6) + (threadIdx.x >> 6);
    int nw = gridDim.x * (blockDim.x >> 6);
#pragma clang loop unroll(disable)
    for (int n = wid; n < N_NODES; n += nw) {
        // n is wave-uniform but LLVM's divergence analysis can't prove it;
        // launder through readfirstlane so "s" constraints get real SGPRs.
        int nu = __builtin_amdgcn_readfirstlane(n);
        const float* hp = h1 + (size_t)nu * 64;
        f32x16 h0, h1v, h2, h3;
        asm volatile("s_load_dwordx16 %0, %4, 0x0\n\t"
                     "s_load_dwordx16 %1, %4, 0x40\n\t"
                     "s_load_dwordx16 %2, %4, 0x80\n\t"
                     "s_load_dwordx16 %3, %4, 0xc0\n\t"
                     "s_waitcnt lgkmcnt(0)"
                     : "=s"(h0), "=s"(h1v), "=s"(h2), "=s"(h3) : "s"(hp));
        float acc = bias;
#pragma unroll
        for (int i = 0; i < 16; ++i) acc = fmaf(h0[i],  R0[i], acc);
#pragma unroll
        for (int i = 0; i < 16; ++i) acc = fmaf(h1v[i], R1[i], acc);
#pragma unroll
        for (int i = 0; i < 16; ++i) acc = fmaf(h2[i],  R2[i], acc);
#pragma unroll
        for (int i = 0; i < 16; ++i) acc = fmaf(h3[i],  R3[i], acc);
        out[(size_t)nu * 64 + lane] = acc;
    }
}

// layer-2 edge kernel v6: wave handles (edge-pair, i-half); 96 weight floats/lane.
// amdgpu_waves_per_eu(2,2) pins occupancy to exactly 2 waves/EU: with no
// occupancy left to gain, the allocator has no incentive to rematerialize
// the weight tuples — they stay VGPR-resident (budget 256).
__global__ __launch_bounds__(256) __attribute__((amdgpu_waves_per_eu(2, 2)))
void k_edge2(const float* __restrict__ h1, const int* __restrict__ ei,
             const float* __restrict__ ea, const float* __restrict__ A2,
             const float* __restrict__ b2, float* __restrict__ out) {
    int lane = threadIdx.x & 63;
    int wid = blockIdx.x * (blockDim.x >> 6) + (threadIdx.x >> 6);
    int nw = gridDim.x * (blockDim.x >> 6);
    // (wid&1)*32 is wave-uniform; launder so pointers built from it can use "s" constraints
    int base = __builtin_amdgcn_readfirstlane((wid & 1) * 32);

    f32x16 W0a, W0b, W1a, W1b, Ba, Bb;
#pragma unroll
    for (int i = 0; i < 16; ++i) {
        W0a[i] = A2[(base + i)      * 64 + lane];
        W0b[i] = A2[(base + 16 + i) * 64 + lane];
        W1a[i] = A2[4096 + (base + i)      * 64 + lane];
        W1b[i] = A2[4096 + (base + 16 + i) * 64 + lane];
        Ba[i]  = b2[(base + i)      * 64 + lane];
        Bb[i]  = b2[(base + 16 + i) * 64 + lane];
    }
    asm volatile("" : "+v"(W0a), "+v"(W0b), "+v"(W1a), "+v"(W1b), "+v"(Ba), "+v"(Bb));

#pragma clang loop unroll(disable)
    for (int p = wid >> 1; p < N_EDGES / 2; p += (nw >> 1)) {
        int2 srcp = ((const int2*)ei)[p];
        int2 dstp = ((const int2*)(ei + N_EDGES))[p];
        float4 eap = ((const float4*)ea)[p];
        int s0 = __builtin_amdgcn_readfirstlane(srcp.x);
        int s1 = __builtin_amdgcn_readfirstlane(srcp.y);
        int d0 = __builtin_amdgcn_readfirstlane(dstp.x);
        int d1 = __builtin_amdgcn_readfirstlane(dstp.y);
        float ea00 = rfl_f(eap.x), ea01 = rfl_f(eap.y);
        float ea10 = rfl_f(eap.z), ea11 = rfl_f(eap.w);
        const float* hp0 = h1 + (size_t)s0 * 64 + base;   // 32 floats each
        const float* hp1 = h1 + (size_t)s1 * 64 + base;
        f32x16 ha, hb, hc, hd;
        asm volatile("s_load_dwordx16 %0, %4, 0x0\n\t"
                     "s_load_dwordx16 %1, %4, 0x40\n\t"
                     "s_load_dwordx16 %2, %5, 0x0\n\t"
                     "s_load_dwordx16 %3, %5, 0x40\n\t"
                     "s_waitcnt lgkmcnt(0)"
                     : "=s"(ha), "=s"(hb), "=s"(hc), "=s"(hd)
                     : "s"(hp0), "s"(hp1));
        float acc0 = 0.f, acc1 = 0.f;
#pragma unroll
        for (int i = 0; i < 16; ++i) {
            float wva = fmaxf(fmaf(ea01, W1a[i], fmaf(ea00, W0a[i], Ba[i])), 0.f);
            acc0 = fmaf(ha[i], wva, acc0);
            float wvb = fmaxf(fmaf(ea11, W1a[i], fmaf(ea10, W0a[i], Ba[i])), 0.f);
            acc1 = fmaf(hc[i], wvb, acc1);
        }
#pragma unroll
        for (int i = 0; i < 16; ++i) {
            float wva = fmaxf(fmaf(ea01, W1b[i], fmaf(ea00, W0b[i], Bb[i])), 0.f);
            acc0 = fmaf(hb[i], wva, acc0);
            float wvb = fmaxf(fmaf(ea11, W1b[i], fmaf(ea10, W0b[i], Bb[i])), 0.f);
            acc1 = fmaf(hd[i], wvb, acc1);
        }
        atomicAdd(&out[(size_t)d0 * 64 + lane], acc0);
        atomicAdd(&out[(size_t)d1 * 64 + lane], acc1);
    }
}

extern "C" void kernel_launch(void* const* d_in, const int* in_sizes, int n_in,
                              void* d_out, int out_size, void* d_ws, size_t ws_size,
                              hipStream_t stream) {
    const float* x     = (const float*)d_in[0];
    const int*   ei    = (const int*)d_in[1];
    const float* ea    = (const float*)d_in[2];
    const float* A1    = (const float*)d_in[3];
    const float* b1    = (const float*)d_in[4];
    const float* A2    = (const float*)d_in[5];
    const float* b2    = (const float*)d_in[6];
    const float* root1 = (const float*)d_in[7];
    const float* bias1 = (const float*)d_in[8];
    const float* root2 = (const float*)d_in[9];
    const float* bias2 = (const float*)d_in[10];
    float* out = (float*)d_out;
    float* h1  = (float*)d_ws;        // N*64 floats = 4 MB scratch

    // 1) h1 = bias1 + x @ root1   (fully initializes ws accumulator)
    k_node1<<<N_NODES * 64 / 256, 256, 0, stream>>>(x, root1, bias1, h1);
    // 2) h1 += scatter-add of layer-1 edge messages
    k_edge1<<<2048, 256, 0, stream>>>(x, ei, ea, A1, b1, h1);
    // 3) out = bias2 + h1 @ root2 (fully initializes d_out)
    k_node2<<<1024, 256, 0, stream>>>(h1, root2, bias2, out);
    // 4) out += scatter-add of layer-2 edge messages
    k_edge2<<<2048, 256, 0, stream>>>(h1, ei, ea, A2, b2, out);
}

// Round 10
// 144.314 us; speedup vs baseline: 1.0784x; 1.0784x over previous
//
#include <hip/hip_runtime.h>

#define N_NODES 16384
#define N_EDGES 65536

typedef float f32x16 __attribute__((ext_vector_type(16)));
typedef float f32x8  __attribute__((ext_vector_type(8)));
typedef float f32x4  __attribute__((ext_vector_type(4)));

__device__ __forceinline__ float rfl_f(float v) {
    int i = __builtin_amdgcn_readfirstlane(__builtin_bit_cast(int, v));
    return __builtin_bit_cast(float, i);
}

// h1[n,o] = bias1[o] + sum_{i<8} x[n,i] * root1[i,o]
__global__ void k_node1(const float* __restrict__ x, const float* __restrict__ root1,
                        const float* __restrict__ bias1, float* __restrict__ h1) {
    int t = blockIdx.x * blockDim.x + threadIdx.x;   // t in [0, N*64)
    int n = t >> 6, o = t & 63;
    float acc = bias1[o];
#pragma unroll
    for (int i = 0; i < 8; ++i)
        acc = fmaf(x[n * 8 + i], root1[i * 64 + o], acc);
    h1[t] = acc;
}

// layer-1 edge kernel: wave per EDGE-PAIR; 24 weight floats/lane (fits easily)
__global__ __launch_bounds__(256)
void k_edge1(const float* __restrict__ x, const int* __restrict__ ei,
             const float* __restrict__ ea, const float* __restrict__ A1,
             const float* __restrict__ b1, float* __restrict__ h1) {
    int lane = threadIdx.x & 63;
    f32x8 W0, W1, BB;
#pragma unroll
    for (int i = 0; i < 8; ++i) {
        W0[i] = A1[i * 64 + lane];
        W1[i] = A1[512 + i * 64 + lane];
        BB[i] = b1[i * 64 + lane];
    }
    asm volatile("" : "+v"(W0), "+v"(W1), "+v"(BB));

    int wid = blockIdx.x * (blockDim.x >> 6) + (threadIdx.x >> 6);
    int nw = gridDim.x * (blockDim.x >> 6);
#pragma clang loop unroll(disable)
    for (int p = wid; p < N_EDGES / 2; p += nw) {
        int2 srcp = ((const int2*)ei)[p];
        int2 dstp = ((const int2*)(ei + N_EDGES))[p];
        float4 eap = ((const float4*)ea)[p];
        int s0 = __builtin_amdgcn_readfirstlane(srcp.x);
        int s1 = __builtin_amdgcn_readfirstlane(srcp.y);
        int d0 = __builtin_amdgcn_readfirstlane(dstp.x);
        int d1 = __builtin_amdgcn_readfirstlane(dstp.y);
        float ea00 = rfl_f(eap.x), ea01 = rfl_f(eap.y);
        float ea10 = rfl_f(eap.z), ea11 = rfl_f(eap.w);
        const float* xp0 = x + (size_t)s0 * 8;
        const float* xp1 = x + (size_t)s1 * 8;
        f32x8 ha, hb;
        asm volatile("s_load_dwordx8 %0, %2, 0x0\n\t"
                     "s_load_dwordx8 %1, %3, 0x0\n\t"
                     "s_waitcnt lgkmcnt(0)"
                     : "=&s"(ha), "=&s"(hb) : "s"(xp0), "s"(xp1));
        float acc0 = 0.f, acc1 = 0.f;
#pragma unroll
        for (int i = 0; i < 8; ++i) {
            float wva = fmaxf(fmaf(ea01, W1[i], fmaf(ea00, W0[i], BB[i])), 0.f);
            acc0 = fmaf(ha[i], wva, acc0);
            float wvb = fmaxf(fmaf(ea11, W1[i], fmaf(ea10, W0[i], BB[i])), 0.f);
            acc1 = fmaf(hb[i], wvb, acc1);
        }
        atomicAdd(&h1[(size_t)d0 * 64 + lane], acc0);
        atomicAdd(&h1[(size_t)d1 * 64 + lane], acc1);
    }
}

// out[n,o] = bias2[o] + sum_{i<64} h1[n,i] * root2[i,o]
__global__ __launch_bounds__(256)
void k_node2(const float* __restrict__ h1, const float* __restrict__ root2,
             const float* __restrict__ bias2, float* __restrict__ out) {
    int lane = threadIdx.x & 63;
    f32x16 R0, R1, R2, R3;
#pragma unroll
    for (int i = 0; i < 16; ++i) {
        R0[i] = root2[(i)      * 64 + lane];
        R1[i] = root2[(16 + i) * 64 + lane];
        R2[i] = root2[(32 + i) * 64 + lane];
        R3[i] = root2[(48 + i) * 64 + lane];
    }
    asm volatile("" : "+v"(R0), "+v"(R1), "+v"(R2), "+v"(R3));
    float bias = bias2[lane];

    int wid = blockIdx.x * (blockDim.x >> 6) + (threadIdx.x >> 6);
    int nw = gridDim.x * (blockDim.x >> 6);
#pragma clang loop unroll(disable)
    for (int n = wid; n < N_NODES; n += nw) {
        int nu = __builtin_amdgcn_readfirstlane(n);   // launder for "s" constraints
        const float* hp = h1 + (size_t)nu * 64;
        f32x16 h0, h1v, h2, h3;
        asm volatile("s_load_dwordx16 %0, %4, 0x0\n\t"
                     "s_load_dwordx16 %1, %4, 0x40\n\t"
                     "s_load_dwordx16 %2, %4, 0x80\n\t"
                     "s_load_dwordx16 %3, %4, 0xc0\n\t"
                     "s_waitcnt lgkmcnt(0)"
                     : "=&s"(h0), "=&s"(h1v), "=&s"(h2), "=&s"(h3) : "s"(hp));
        float acc = bias;
#pragma unroll
        for (int i = 0; i < 16; ++i) acc = fmaf(h0[i],  R0[i], acc);
#pragma unroll
        for (int i = 0; i < 16; ++i) acc = fmaf(h1v[i], R1[i], acc);
#pragma unroll
        for (int i = 0; i < 16; ++i) acc = fmaf(h2[i],  R2[i], acc);
#pragma unroll
        for (int i = 0; i < 16; ++i) acc = fmaf(h3[i],  R3[i], acc);
        out[(size_t)nu * 64 + lane] = acc;
    }
}

// layer-2 edge kernel v7: weights in LDS (transposed, padded), read per-iteration
// with ds_read_b128 + immediate offsets. Block owns one i-half (32 i's);
// wave handles an edge pair. No persistent per-lane weight state -> no remat,
// no AGPR round-trip. h half-rows via scalar loads (SGPR budget: 64).
__global__ __launch_bounds__(256)
void k_edge2(const float* __restrict__ h1, const int* __restrict__ ei,
             const float* __restrict__ ea, const float* __restrict__ A2,
             const float* __restrict__ b2, float* __restrict__ out) {
    // WT[arr][o][i_local]: arr in {w0,w1,bb}, o=0..63, i_local=0..31, row stride 36
    // dwords (144 B: 16B-aligned, bank spread (4o+i)%32 -> optimal for b128).
    __shared__ __align__(16) float WT[3 * 64 * 36];   // 27648 B
    int half = blockIdx.x & 1;                        // block's i-half (uniform)
    for (int j = threadIdx.x; j < 2048; j += 256) {   // stage coalesced, transpose
        int i = j >> 6, o = j & 63;
        WT[o * 36 + i]                = A2[half * 2048 + j];
        WT[64 * 36 + o * 36 + i]      = A2[4096 + half * 2048 + j];
        WT[2 * 64 * 36 + o * 36 + i]  = b2[half * 2048 + j];
    }
    __syncthreads();

    int lane = threadIdx.x & 63;
    int base = half * 32;                              // h-row float offset (scalar)
    unsigned laddr = (unsigned)(uintptr_t)WT + lane * 144;

    int g = blockIdx.x >> 1;                           // 0..1023 within half-group
    int wslot = g * 4 + (threadIdx.x >> 6);            // 0..4095
#pragma clang loop unroll(disable)
    for (int p = wslot; p < N_EDGES / 2; p += 4096) {
        int2 srcp = ((const int2*)ei)[p];
        int2 dstp = ((const int2*)(ei + N_EDGES))[p];
        float4 eap = ((const float4*)ea)[p];
        int s0 = __builtin_amdgcn_readfirstlane(srcp.x);
        int s1 = __builtin_amdgcn_readfirstlane(srcp.y);
        int d0 = __builtin_amdgcn_readfirstlane(dstp.x);
        int d1 = __builtin_amdgcn_readfirstlane(dstp.y);
        float ea00 = rfl_f(eap.x), ea01 = rfl_f(eap.y);
        float ea10 = rfl_f(eap.z), ea11 = rfl_f(eap.w);
        const float* hp0 = h1 + (size_t)s0 * 64 + base;
        const float* hp1 = h1 + (size_t)s1 * 64 + base;

        f32x16 ha, hb, hc, hd;            // h half-rows: edge0 (ha,hb), edge1 (hc,hd)
        asm volatile("s_load_dwordx16 %0, %4, 0x0\n\t"
                     "s_load_dwordx16 %1, %4, 0x40\n\t"
                     "s_load_dwordx16 %2, %5, 0x0\n\t"
                     "s_load_dwordx16 %3, %5, 0x40"
                     : "=&s"(ha), "=&s"(hb), "=&s"(hc), "=&s"(hd)
                     : "s"(hp0), "s"(hp1));

        f32x4 wa[8], wb[8], wc[8];        // w0,w1,bb for i_local 0..31
        asm volatile(                      // chunk A: i_local 0..15
            "ds_read_b128 %0, %12 offset:0\n\t"
            "ds_read_b128 %1, %12 offset:16\n\t"
            "ds_read_b128 %2, %12 offset:32\n\t"
            "ds_read_b128 %3, %12 offset:48\n\t"
            "ds_read_b128 %4, %12 offset:9216\n\t"
            "ds_read_b128 %5, %12 offset:9232\n\t"
            "ds_read_b128 %6, %12 offset:9248\n\t"
            "ds_read_b128 %7, %12 offset:9264\n\t"
            "ds_read_b128 %8, %12 offset:18432\n\t"
            "ds_read_b128 %9, %12 offset:18448\n\t"
            "ds_read_b128 %10, %12 offset:18464\n\t"
            "ds_read_b128 %11, %12 offset:18480"
            : "=&v"(wa[0]), "=&v"(wa[1]), "=&v"(wa[2]), "=&v"(wa[3]),
              "=&v"(wb[0]), "=&v"(wb[1]), "=&v"(wb[2]), "=&v"(wb[3]),
              "=&v"(wc[0]), "=&v"(wc[1]), "=&v"(wc[2]), "=&v"(wc[3])
            : "v"(laddr));
        asm volatile(                      // chunk B: i_local 16..31
            "ds_read_b128 %0, %12 offset:64\n\t"
            "ds_read_b128 %1, %12 offset:80\n\t"
            "ds_read_b128 %2, %12 offset:96\n\t"
            "ds_read_b128 %3, %12 offset:112\n\t"
            "ds_read_b128 %4, %12 offset:9280\n\t"
            "ds_read_b128 %5, %12 offset:9296\n\t"
            "ds_read_b128 %6, %12 offset:9312\n\t"
            "ds_read_b128 %7, %12 offset:9328\n\t"
            "ds_read_b128 %8, %12 offset:18496\n\t"
            "ds_read_b128 %9, %12 offset:18512\n\t"
            "ds_read_b128 %10, %12 offset:18528\n\t"
            "ds_read_b128 %11, %12 offset:18544"
            : "=&v"(wa[4]), "=&v"(wa[5]), "=&v"(wa[6]), "=&v"(wa[7]),
              "=&v"(wb[4]), "=&v"(wb[5]), "=&v"(wb[6]), "=&v"(wb[7]),
              "=&v"(wc[4]), "=&v"(wc[5]), "=&v"(wc[6]), "=&v"(wc[7])
            : "v"(laddr));
        // Single drain; pass-through operands order every consumer after the wait
        // (rule #18: plain "memory"/volatile does NOT order dependent reg-only uses).
        asm volatile("s_waitcnt lgkmcnt(0)"
            : "+v"(wa[0]), "+v"(wa[1]), "+v"(wa[2]), "+v"(wa[3]),
              "+v"(wa[4]), "+v"(wa[5]), "+v"(wa[6]), "+v"(wa[7]),
              "+v"(wb[0]), "+v"(wb[1]), "+v"(wb[2]), "+v"(wb[3]),
              "+v"(wb[4]), "+v"(wb[5]), "+v"(wb[6]), "+v"(wb[7]),
              "+v"(wc[0]), "+v"(wc[1]), "+v"(wc[2]), "+v"(wc[3]),
              "+v"(wc[4]), "+v"(wc[5]), "+v"(wc[6]), "+v"(wc[7]),
              "+s"(ha), "+s"(hb), "+s"(hc), "+s"(hd));

        float acc0 = 0.f, acc1 = 0.f;
#pragma unroll
        for (int q = 0; q < 4; ++q) {
#pragma unroll
            for (int k = 0; k < 4; ++k) {
                float wv0 = fmaxf(fmaf(ea01, wb[q][k], fmaf(ea00, wa[q][k], wc[q][k])), 0.f);
                acc0 = fmaf(ha[q * 4 + k], wv0, acc0);
                float wv1 = fmaxf(fmaf(ea11, wb[q][k], fmaf(ea10, wa[q][k], wc[q][k])), 0.f);
                acc1 = fmaf(hc[q * 4 + k], wv1, acc1);
            }
        }
#pragma unroll
        for (int q = 4; q < 8; ++q) {
#pragma unroll
            for (int k = 0; k < 4; ++k) {
                float wv0 = fmaxf(fmaf(ea01, wb[q][k], fmaf(ea00, wa[q][k], wc[q][k])), 0.f);
                acc0 = fmaf(hb[(q - 4) * 4 + k], wv0, acc0);
                float wv1 = fmaxf(fmaf(ea11, wb[q][k], fmaf(ea10, wa[q][k], wc[q][k])), 0.f);
                acc1 = fmaf(hd[(q - 4) * 4 + k], wv1, acc1);
            }
        }
        atomicAdd(&out[(size_t)d0 * 64 + lane], acc0);
        atomicAdd(&out[(size_t)d1 * 64 + lane], acc1);
    }
}

extern "C" void kernel_launch(void* const* d_in, const int* in_sizes, int n_in,
                              void* d_out, int out_size, void* d_ws, size_t ws_size,
                              hipStream_t stream) {
    const float* x     = (const float*)d_in[0];
    const int*   ei    = (const int*)d_in[1];
    const float* ea    = (const float*)d_in[2];
    const float* A1    = (const float*)d_in[3];
    const float* b1    = (const float*)d_in[4];
    const float* A2    = (const float*)d_in[5];
    const float* b2    = (const float*)d_in[6];
    const float* root1 = (const float*)d_in[7];
    const float* bias1 = (const float*)d_in[8];
    const float* root2 = (const float*)d_in[9];
    const float* bias2 = (const float*)d_in[10];
    float* out = (float*)d_out;
    float* h1  = (float*)d_ws;        // N*64 floats = 4 MB scratch

    // 1) h1 = bias1 + x @ root1   (fully initializes ws accumulator)
    k_node1<<<N_NODES * 64 / 256, 256, 0, stream>>>(x, root1, bias1, h1);
    // 2) h1 += scatter-add of layer-1 edge messages
    k_edge1<<<2048, 256, 0, stream>>>(x, ei, ea, A1, b1, h1);
    // 3) out = bias2 + h1 @ root2 (fully initializes d_out)
    k_node2<<<1024, 256, 0, stream>>>(h1, root2, bias2, out);
    // 4) out += scatter-add of layer-2 edge messages
    k_edge2<<<2048, 256, 0, stream>>>(h1, ei, ea, A2, b2, out);
}

// Round 11
// 138.508 us; speedup vs baseline: 1.1236x; 1.0419x over previous
//
#include <hip/hip_runtime.h>

#define N_NODES 16384
#define N_EDGES 65536

typedef float f32x16 __attribute__((ext_vector_type(16)));
typedef float f32x8  __attribute__((ext_vector_type(8)));
typedef float f32x4  __attribute__((ext_vector_type(4)));

__device__ __forceinline__ float rfl_f(float v) {
    int i = __builtin_amdgcn_readfirstlane(__builtin_bit_cast(int, v));
    return __builtin_bit_cast(float, i);
}

// h1[n,o] = bias1[o] + sum_{i<8} x[n,i] * root1[i,o]
__global__ void k_node1(const float* __restrict__ x, const float* __restrict__ root1,
                        const float* __restrict__ bias1, float* __restrict__ h1) {
    int t = blockIdx.x * blockDim.x + threadIdx.x;   // t in [0, N*64)
    int n = t >> 6, o = t & 63;
    float acc = bias1[o];
#pragma unroll
    for (int i = 0; i < 8; ++i)
        acc = fmaf(x[n * 8 + i], root1[i * 64 + o], acc);
    h1[t] = acc;
}

// layer-1 edge kernel: wave per EDGE-PAIR; 24 weight floats/lane (fits easily)
__global__ __launch_bounds__(256)
void k_edge1(const float* __restrict__ x, const int* __restrict__ ei,
             const float* __restrict__ ea, const float* __restrict__ A1,
             const float* __restrict__ b1, float* __restrict__ h1) {
    int lane = threadIdx.x & 63;
    f32x8 W0, W1, BB;
#pragma unroll
    for (int i = 0; i < 8; ++i) {
        W0[i] = A1[i * 64 + lane];
        W1[i] = A1[512 + i * 64 + lane];
        BB[i] = b1[i * 64 + lane];
    }
    asm volatile("" : "+v"(W0), "+v"(W1), "+v"(BB));

    int wid = blockIdx.x * (blockDim.x >> 6) + (threadIdx.x >> 6);
    int nw = gridDim.x * (blockDim.x >> 6);
#pragma clang loop unroll(disable)
    for (int p = wid; p < N_EDGES / 2; p += nw) {
        int2 srcp = ((const int2*)ei)[p];
        int2 dstp = ((const int2*)(ei + N_EDGES))[p];
        float4 eap = ((const float4*)ea)[p];
        int s0 = __builtin_amdgcn_readfirstlane(srcp.x);
        int s1 = __builtin_amdgcn_readfirstlane(srcp.y);
        int d0 = __builtin_amdgcn_readfirstlane(dstp.x);
        int d1 = __builtin_amdgcn_readfirstlane(dstp.y);
        float ea00 = rfl_f(eap.x), ea01 = rfl_f(eap.y);
        float ea10 = rfl_f(eap.z), ea11 = rfl_f(eap.w);
        const float* xp0 = x + (size_t)s0 * 8;
        const float* xp1 = x + (size_t)s1 * 8;
        f32x8 ha, hb;
        asm volatile("s_load_dwordx8 %0, %2, 0x0\n\t"
                     "s_load_dwordx8 %1, %3, 0x0\n\t"
                     "s_waitcnt lgkmcnt(0)"
                     : "=&s"(ha), "=&s"(hb) : "s"(xp0), "s"(xp1));
        float acc0 = 0.f, acc1 = 0.f;
#pragma unroll
        for (int i = 0; i < 8; ++i) {
            float wva = fmaxf(fmaf(ea01, W1[i], fmaf(ea00, W0[i], BB[i])), 0.f);
            acc0 = fmaf(ha[i], wva, acc0);
            float wvb = fmaxf(fmaf(ea11, W1[i], fmaf(ea10, W0[i], BB[i])), 0.f);
            acc1 = fmaf(hb[i], wvb, acc1);
        }
        atomicAdd(&h1[(size_t)d0 * 64 + lane], acc0);
        atomicAdd(&h1[(size_t)d1 * 64 + lane], acc1);
    }
}

// out[n,o] = bias2[o] + sum_{i<64} h1[n,i] * root2[i,o]
__global__ __launch_bounds__(256)
void k_node2(const float* __restrict__ h1, const float* __restrict__ root2,
             const float* __restrict__ bias2, float* __restrict__ out) {
    int lane = threadIdx.x & 63;
    f32x16 R0, R1, R2, R3;
#pragma unroll
    for (int i = 0; i < 16; ++i) {
        R0[i] = root2[(i)      * 64 + lane];
        R1[i] = root2[(16 + i) * 64 + lane];
        R2[i] = root2[(32 + i) * 64 + lane];
        R3[i] = root2[(48 + i) * 64 + lane];
    }
    asm volatile("" : "+v"(R0), "+v"(R1), "+v"(R2), "+v"(R3));
    float bias = bias2[lane];

    int wid = blockIdx.x * (blockDim.x >> 6) + (threadIdx.x >> 6);
    int nw = gridDim.x * (blockDim.x >> 6);
#pragma clang loop unroll(disable)
    for (int n = wid; n < N_NODES; n += nw) {
        int nu = __builtin_amdgcn_readfirstlane(n);   // launder for "s" constraints
        const float* hp = h1 + (size_t)nu * 64;
        f32x16 h0, h1v, h2, h3;
        asm volatile("s_load_dwordx16 %0, %4, 0x0\n\t"
                     "s_load_dwordx16 %1, %4, 0x40\n\t"
                     "s_load_dwordx16 %2, %4, 0x80\n\t"
                     "s_load_dwordx16 %3, %4, 0xc0\n\t"
                     "s_waitcnt lgkmcnt(0)"
                     : "=&s"(h0), "=&s"(h1v), "=&s"(h2), "=&s"(h3) : "s"(hp));
        float acc = bias;
#pragma unroll
        for (int i = 0; i < 16; ++i) acc = fmaf(h0[i],  R0[i], acc);
#pragma unroll
        for (int i = 0; i < 16; ++i) acc = fmaf(h1v[i], R1[i], acc);
#pragma unroll
        for (int i = 0; i < 16; ++i) acc = fmaf(h2[i],  R2[i], acc);
#pragma unroll
        for (int i = 0; i < 16; ++i) acc = fmaf(h3[i],  R3[i], acc);
        out[(size_t)nu * 64 + lane] = acc;
    }
}

// layer-2 edge kernel v9: LDS weights + SOFTWARE PIPELINE.
// Per iter: issue 24 ds_reads; compute next-iter h pointers; ONE lgkmcnt(0)
// drain (weights + h prefetched LAST iter); FMA half-1 (ha,hc); reload ha,hc
// for next iter (s_load issued, NOT waited); FMA half-2 (hb,hd); reload hb,hd;
// atomics. h-load latency hides under half-2 + atomics + next ds window.
// Meta prefetched one iteration ahead (compiler-managed vmcnt), index clamped.
__global__ __launch_bounds__(256)
void k_edge2(const float* __restrict__ h1, const int* __restrict__ ei,
             const float* __restrict__ ea, const float* __restrict__ A2,
             const float* __restrict__ b2, float* __restrict__ out) {
    // WT[arr][o][i_local]: row stride 36 dwords (144 B, 16B-aligned)
    __shared__ __align__(16) float WT[3 * 64 * 36];   // 27648 B
    int half = blockIdx.x & 1;
    for (int j = threadIdx.x; j < 2048; j += 256) {
        int i = j >> 6, o = j & 63;
        WT[o * 36 + i]               = A2[half * 2048 + j];
        WT[64 * 36 + o * 36 + i]     = A2[4096 + half * 2048 + j];
        WT[2 * 64 * 36 + o * 36 + i] = b2[half * 2048 + j];
    }
    __syncthreads();

    int lane = threadIdx.x & 63;
    int base = __builtin_amdgcn_readfirstlane(half * 32);
    unsigned laddr = (unsigned)(uintptr_t)WT + lane * 144;

    int g = blockIdx.x >> 1;
    int wslot = g * 4 + (threadIdx.x >> 6);            // 0..4095; 8 iters/wave

    f32x16 ha, hb, hc, hd;           // SGPR h half-rows: edge0=(ha,hb) edge1=(hc,hd)

    // ---- prologue: meta(0), issue h(0), prefetch meta(1) ----
    int p0 = wslot;
    int2   dst_c = ((const int2*)(ei + N_EDGES))[p0];
    float4 ea_c  = ((const float4*)ea)[p0];
    {
        int2 src0 = ((const int2*)ei)[p0];
        int s0 = __builtin_amdgcn_readfirstlane(src0.x);
        int s1 = __builtin_amdgcn_readfirstlane(src0.y);
        const float* hp0 = h1 + (size_t)s0 * 64 + base;
        const float* hp1 = h1 + (size_t)s1 * 64 + base;
        asm volatile("s_load_dwordx16 %0, %4, 0x0\n\t"
                     "s_load_dwordx16 %1, %4, 0x40\n\t"
                     "s_load_dwordx16 %2, %5, 0x0\n\t"
                     "s_load_dwordx16 %3, %5, 0x40"
                     : "=&s"(ha), "=&s"(hb), "=&s"(hc), "=&s"(hd)
                     : "s"(hp0), "s"(hp1));
    }
    int pn = p0 + 4096; if (pn > N_EDGES / 2 - 1) pn = N_EDGES / 2 - 1;
    int2   src_n = ((const int2*)ei)[pn];
    int2   dst_n = ((const int2*)(ei + N_EDGES))[pn];
    float4 ea_n  = ((const float4*)ea)[pn];

#pragma clang loop unroll(disable)
    for (int p = wslot; p < N_EDGES / 2; p += 4096) {
        f32x4 wa[8], wb[8], wc[8];
        asm volatile(                      // chunk A: i_local 0..15
            "ds_read_b128 %0, %12 offset:0\n\t"
            "ds_read_b128 %1, %12 offset:16\n\t"
            "ds_read_b128 %2, %12 offset:32\n\t"
            "ds_read_b128 %3, %12 offset:48\n\t"
            "ds_read_b128 %4, %12 offset:9216\n\t"
            "ds_read_b128 %5, %12 offset:9232\n\t"
            "ds_read_b128 %6, %12 offset:9248\n\t"
            "ds_read_b128 %7, %12 offset:9264\n\t"
            "ds_read_b128 %8, %12 offset:18432\n\t"
            "ds_read_b128 %9, %12 offset:18448\n\t"
            "ds_read_b128 %10, %12 offset:18464\n\t"
            "ds_read_b128 %11, %12 offset:18480"
            : "=&v"(wa[0]), "=&v"(wa[1]), "=&v"(wa[2]), "=&v"(wa[3]),
              "=&v"(wb[0]), "=&v"(wb[1]), "=&v"(wb[2]), "=&v"(wb[3]),
              "=&v"(wc[0]), "=&v"(wc[1]), "=&v"(wc[2]), "=&v"(wc[3])
            : "v"(laddr));
        asm volatile(                      // chunk B: i_local 16..31
            "ds_read_b128 %0, %12 offset:64\n\t"
            "ds_read_b128 %1, %12 offset:80\n\t"
            "ds_read_b128 %2, %12 offset:96\n\t"
            "ds_read_b128 %3, %12 offset:112\n\t"
            "ds_read_b128 %4, %12 offset:9280\n\t"
            "ds_read_b128 %5, %12 offset:9296\n\t"
            "ds_read_b128 %6, %12 offset:9312\n\t"
            "ds_read_b128 %7, %12 offset:9328\n\t"
            "ds_read_b128 %8, %12 offset:18496\n\t"
            "ds_read_b128 %9, %12 offset:18512\n\t"
            "ds_read_b128 %10, %12 offset:18528\n\t"
            "ds_read_b128 %11, %12 offset:18544"
            : "=&v"(wa[4]), "=&v"(wa[5]), "=&v"(wa[6]), "=&v"(wa[7]),
              "=&v"(wb[4]), "=&v"(wb[5]), "=&v"(wb[6]), "=&v"(wb[7]),
              "=&v"(wc[4]), "=&v"(wc[5]), "=&v"(wc[6]), "=&v"(wc[7])
            : "v"(laddr));

        // next-iter h pointers (SALU work fills the ds window)
        int s0n = __builtin_amdgcn_readfirstlane(src_n.x);
        int s1n = __builtin_amdgcn_readfirstlane(src_n.y);
        const float* hpn0 = h1 + (size_t)s0n * 64 + base;
        const float* hpn1 = h1 + (size_t)s1n * 64 + base;

        // single drain: weights (this iter) + h (prefetched last iter / prologue)
        asm volatile("s_waitcnt lgkmcnt(0)"
            : "+v"(wa[0]), "+v"(wa[1]), "+v"(wa[2]), "+v"(wa[3]),
              "+v"(wa[4]), "+v"(wa[5]), "+v"(wa[6]), "+v"(wa[7]),
              "+v"(wb[0]), "+v"(wb[1]), "+v"(wb[2]), "+v"(wb[3]),
              "+v"(wb[4]), "+v"(wb[5]), "+v"(wb[6]), "+v"(wb[7]),
              "+v"(wc[0]), "+v"(wc[1]), "+v"(wc[2]), "+v"(wc[3]),
              "+v"(wc[4]), "+v"(wc[5]), "+v"(wc[6]), "+v"(wc[7]),
              "+s"(ha), "+s"(hb), "+s"(hc), "+s"(hd));

        float acc0 = 0.f, acc1 = 0.f;
        // FMA half 1: i_local 0..15 (consumes ha, hc)
#pragma unroll
        for (int q = 0; q < 4; ++q) {
#pragma unroll
            for (int k = 0; k < 4; ++k) {
                float wv0 = fmaxf(fmaf(ea_c.y, wb[q][k], fmaf(ea_c.x, wa[q][k], wc[q][k])), 0.f);
                acc0 = fmaf(ha[q * 4 + k], wv0, acc0);
                float wv1 = fmaxf(fmaf(ea_c.w, wb[q][k], fmaf(ea_c.z, wa[q][k], wc[q][k])), 0.f);
                acc1 = fmaf(hc[q * 4 + k], wv1, acc1);
            }
        }
        // B1: ha,hc done -> issue next-iter loads into them (latency hides below)
        asm volatile("s_load_dwordx16 %0, %2, 0x0\n\t"
                     "s_load_dwordx16 %1, %3, 0x0"
                     : "=&s"(ha), "=&s"(hc) : "s"(hpn0), "s"(hpn1));
        // FMA half 2: i_local 16..31 (consumes hb, hd)
#pragma unroll
        for (int q = 4; q < 8; ++q) {
#pragma unroll
            for (int k = 0; k < 4; ++k) {
                float wv0 = fmaxf(fmaf(ea_c.y, wb[q][k], fmaf(ea_c.x, wa[q][k], wc[q][k])), 0.f);
                acc0 = fmaf(hb[(q - 4) * 4 + k], wv0, acc0);
                float wv1 = fmaxf(fmaf(ea_c.w, wb[q][k], fmaf(ea_c.z, wa[q][k], wc[q][k])), 0.f);
                acc1 = fmaf(hd[(q - 4) * 4 + k], wv1, acc1);
            }
        }
        // B2: hb,hd done -> issue next-iter loads
        asm volatile("s_load_dwordx16 %0, %2, 0x40\n\t"
                     "s_load_dwordx16 %1, %3, 0x40"
                     : "=&s"(hb), "=&s"(hd) : "s"(hpn0), "s"(hpn1));

        atomicAdd(&out[(size_t)dst_c.x * 64 + lane], acc0);
        atomicAdd(&out[(size_t)dst_c.y * 64 + lane], acc1);

        // rotate meta and prefetch iter t+2 (clamped in-bounds; tail junk unused)
        dst_c = dst_n; ea_c = ea_n;
        int pn2 = p + 8192; if (pn2 > N_EDGES / 2 - 1) pn2 = N_EDGES / 2 - 1;
        src_n = ((const int2*)ei)[pn2];
        dst_n = ((const int2*)(ei + N_EDGES))[pn2];
        ea_n  = ((const float4*)ea)[pn2];
    }
}

extern "C" void kernel_launch(void* const* d_in, const int* in_sizes, int n_in,
                              void* d_out, int out_size, void* d_ws, size_t ws_size,
                              hipStream_t stream) {
    const float* x     = (const float*)d_in[0];
    const int*   ei    = (const int*)d_in[1];
    const float* ea    = (const float*)d_in[2];
    const float* A1    = (const float*)d_in[3];
    const float* b1    = (const float*)d_in[4];
    const float* A2    = (const float*)d_in[5];
    const float* b2    = (const float*)d_in[6];
    const float* root1 = (const float*)d_in[7];
    const float* bias1 = (const float*)d_in[8];
    const float* root2 = (const float*)d_in[9];
    const float* bias2 = (const float*)d_in[10];
    float* out = (float*)d_out;
    float* h1  = (float*)d_ws;        // N*64 floats = 4 MB scratch

    // 1) h1 = bias1 + x @ root1   (fully initializes ws accumulator)
    k_node1<<<N_NODES * 64 / 256, 256, 0, stream>>>(x, root1, bias1, h1);
    // 2) h1 += scatter-add of layer-1 edge messages
    k_edge1<<<2048, 256, 0, stream>>>(x, ei, ea, A1, b1, h1);
    // 3) out = bias2 + h1 @ root2 (fully initializes d_out)
    k_node2<<<1024, 256, 0, stream>>>(h1, root2, bias2, out);
    // 4) out += scatter-add of layer-2 edge messages
    k_edge2<<<2048, 256, 0, stream>>>(h1, ei, ea, A2, b2, out);
}

// Round 12
// 138.129 us; speedup vs baseline: 1.1267x; 1.0027x over previous
//
#include <hip/hip_runtime.h>

#define N_NODES 16384
#define N_EDGES 65536

typedef float f32x16 __attribute__((ext_vector_type(16)));
typedef float f32x8  __attribute__((ext_vector_type(8)));
typedef float f32x4  __attribute__((ext_vector_type(4)));
typedef float f32x2  __attribute__((ext_vector_type(2)));

__device__ __forceinline__ float rfl_f(float v) {
    int i = __builtin_amdgcn_readfirstlane(__builtin_bit_cast(int, v));
    return __builtin_bit_cast(float, i);
}

// h1[n,o] = bias1[o] + sum_{i<8} x[n,i] * root1[i,o]
__global__ void k_node1(const float* __restrict__ x, const float* __restrict__ root1,
                        const float* __restrict__ bias1, float* __restrict__ h1) {
    int t = blockIdx.x * blockDim.x + threadIdx.x;   // t in [0, N*64)
    int n = t >> 6, o = t & 63;
    float acc = bias1[o];
#pragma unroll
    for (int i = 0; i < 8; ++i)
        acc = fmaf(x[n * 8 + i], root1[i * 64 + o], acc);
    h1[t] = acc;
}

// layer-1 edge kernel: wave per EDGE-PAIR; packed-f32 MLP (v_pk_fma/v_pk_max)
__global__ __launch_bounds__(256)
void k_edge1(const float* __restrict__ x, const int* __restrict__ ei,
             const float* __restrict__ ea, const float* __restrict__ A1,
             const float* __restrict__ b1, float* __restrict__ h1) {
    int lane = threadIdx.x & 63;
    f32x8 W0, W1, BB;
#pragma unroll
    for (int i = 0; i < 8; ++i) {
        W0[i] = A1[i * 64 + lane];
        W1[i] = A1[512 + i * 64 + lane];
        BB[i] = b1[i * 64 + lane];
    }
    asm volatile("" : "+v"(W0), "+v"(W1), "+v"(BB));

    int wid = blockIdx.x * (blockDim.x >> 6) + (threadIdx.x >> 6);
    int nw = gridDim.x * (blockDim.x >> 6);
#pragma clang loop unroll(disable)
    for (int p = wid; p < N_EDGES / 2; p += nw) {
        int2 srcp = ((const int2*)ei)[p];
        int2 dstp = ((const int2*)(ei + N_EDGES))[p];
        float4 eap = ((const float4*)ea)[p];
        int s0 = __builtin_amdgcn_readfirstlane(srcp.x);
        int s1 = __builtin_amdgcn_readfirstlane(srcp.y);
        int d0 = __builtin_amdgcn_readfirstlane(dstp.x);
        int d1 = __builtin_amdgcn_readfirstlane(dstp.y);
        f32x2 e00 = {rfl_f(eap.x), rfl_f(eap.x)};
        f32x2 e01 = {rfl_f(eap.y), rfl_f(eap.y)};
        f32x2 e10 = {rfl_f(eap.z), rfl_f(eap.z)};
        f32x2 e11 = {rfl_f(eap.w), rfl_f(eap.w)};
        const float* xp0 = x + (size_t)s0 * 8;
        const float* xp1 = x + (size_t)s1 * 8;
        f32x8 ha, hb;
        asm volatile("s_load_dwordx8 %0, %2, 0x0\n\t"
                     "s_load_dwordx8 %1, %3, 0x0\n\t"
                     "s_waitcnt lgkmcnt(0)"
                     : "=&s"(ha), "=&s"(hb) : "s"(xp0), "s"(xp1));
        f32x2 acc0 = {0.f, 0.f}, acc1 = {0.f, 0.f};
        const f32x2 z2 = {0.f, 0.f};
#pragma unroll
        for (int k = 0; k < 4; ++k) {
            f32x2 w0p = {W0[2 * k], W0[2 * k + 1]};
            f32x2 w1p = {W1[2 * k], W1[2 * k + 1]};
            f32x2 bp  = {BB[2 * k], BB[2 * k + 1]};
            f32x2 wv0 = __builtin_elementwise_max(
                __builtin_elementwise_fma(e01, w1p,
                    __builtin_elementwise_fma(e00, w0p, bp)), z2);
            f32x2 h0p = {ha[2 * k], ha[2 * k + 1]};
            acc0 = __builtin_elementwise_fma(h0p, wv0, acc0);
            f32x2 wv1 = __builtin_elementwise_max(
                __builtin_elementwise_fma(e11, w1p,
                    __builtin_elementwise_fma(e10, w0p, bp)), z2);
            f32x2 h1p = {hb[2 * k], hb[2 * k + 1]};
            acc1 = __builtin_elementwise_fma(h1p, wv1, acc1);
        }
        atomicAdd(&h1[(size_t)d0 * 64 + lane], acc0[0] + acc0[1]);
        atomicAdd(&h1[(size_t)d1 * 64 + lane], acc1[0] + acc1[1]);
    }
}

// out[n,o] = bias2[o] + sum_{i<64} h1[n,i] * root2[i,o]  (packed f32)
__global__ __launch_bounds__(256)
void k_node2(const float* __restrict__ h1, const float* __restrict__ root2,
             const float* __restrict__ bias2, float* __restrict__ out) {
    int lane = threadIdx.x & 63;
    f32x16 R0, R1, R2, R3;
#pragma unroll
    for (int i = 0; i < 16; ++i) {
        R0[i] = root2[(i)      * 64 + lane];
        R1[i] = root2[(16 + i) * 64 + lane];
        R2[i] = root2[(32 + i) * 64 + lane];
        R3[i] = root2[(48 + i) * 64 + lane];
    }
    asm volatile("" : "+v"(R0), "+v"(R1), "+v"(R2), "+v"(R3));
    float bias = bias2[lane];

    int wid = blockIdx.x * (blockDim.x >> 6) + (threadIdx.x >> 6);
    int nw = gridDim.x * (blockDim.x >> 6);
#pragma clang loop unroll(disable)
    for (int n = wid; n < N_NODES; n += nw) {
        int nu = __builtin_amdgcn_readfirstlane(n);   // launder for "s" constraints
        const float* hp = h1 + (size_t)nu * 64;
        f32x16 h0, h1v, h2, h3;
        asm volatile("s_load_dwordx16 %0, %4, 0x0\n\t"
                     "s_load_dwordx16 %1, %4, 0x40\n\t"
                     "s_load_dwordx16 %2, %4, 0x80\n\t"
                     "s_load_dwordx16 %3, %4, 0xc0\n\t"
                     "s_waitcnt lgkmcnt(0)"
                     : "=&s"(h0), "=&s"(h1v), "=&s"(h2), "=&s"(h3) : "s"(hp));
        f32x2 accp = {bias, 0.f};
#pragma unroll
        for (int k = 0; k < 8; ++k) {
            f32x2 hp0 = {h0[2 * k], h0[2 * k + 1]};
            f32x2 rp0 = {R0[2 * k], R0[2 * k + 1]};
            accp = __builtin_elementwise_fma(hp0, rp0, accp);
            f32x2 hp1 = {h1v[2 * k], h1v[2 * k + 1]};
            f32x2 rp1 = {R1[2 * k], R1[2 * k + 1]};
            accp = __builtin_elementwise_fma(hp1, rp1, accp);
            f32x2 hp2 = {h2[2 * k], h2[2 * k + 1]};
            f32x2 rp2 = {R2[2 * k], R2[2 * k + 1]};
            accp = __builtin_elementwise_fma(hp2, rp2, accp);
            f32x2 hp3 = {h3[2 * k], h3[2 * k + 1]};
            f32x2 rp3 = {R3[2 * k], R3[2 * k + 1]};
            accp = __builtin_elementwise_fma(hp3, rp3, accp);
        }
        out[(size_t)nu * 64 + lane] = accp[0] + accp[1];
    }
}

// layer-2 edge kernel v10: LDS weights + software pipeline (R11) + PACKED f32
// inner loop: v_pk_fma_f32/v_pk_max_f32 halve VALU issue (2 ops per edge,i).
__global__ __launch_bounds__(256)
void k_edge2(const float* __restrict__ h1, const int* __restrict__ ei,
             const float* __restrict__ ea, const float* __restrict__ A2,
             const float* __restrict__ b2, float* __restrict__ out) {
    __shared__ __align__(16) float WT[3 * 64 * 36];   // 27648 B, row stride 36 dwords
    int half = blockIdx.x & 1;
    for (int j = threadIdx.x; j < 2048; j += 256) {
        int i = j >> 6, o = j & 63;
        WT[o * 36 + i]               = A2[half * 2048 + j];
        WT[64 * 36 + o * 36 + i]     = A2[4096 + half * 2048 + j];
        WT[2 * 64 * 36 + o * 36 + i] = b2[half * 2048 + j];
    }
    __syncthreads();

    int lane = threadIdx.x & 63;
    int base = __builtin_amdgcn_readfirstlane(half * 32);
    unsigned laddr = (unsigned)(uintptr_t)WT + lane * 144;

    int g = blockIdx.x >> 1;
    int wslot = g * 4 + (threadIdx.x >> 6);            // 0..4095; 8 iters/wave

    f32x16 ha, hb, hc, hd;           // SGPR h half-rows: edge0=(ha,hb) edge1=(hc,hd)

    // ---- prologue: meta(0), issue h(0), prefetch meta(1) ----
    int p0 = wslot;
    int2   dst_c = ((const int2*)(ei + N_EDGES))[p0];
    float4 ea_c  = ((const float4*)ea)[p0];
    {
        int2 src0 = ((const int2*)ei)[p0];
        int s0 = __builtin_amdgcn_readfirstlane(src0.x);
        int s1 = __builtin_amdgcn_readfirstlane(src0.y);
        const float* hp0 = h1 + (size_t)s0 * 64 + base;
        const float* hp1 = h1 + (size_t)s1 * 64 + base;
        asm volatile("s_load_dwordx16 %0, %4, 0x0\n\t"
                     "s_load_dwordx16 %1, %4, 0x40\n\t"
                     "s_load_dwordx16 %2, %5, 0x0\n\t"
                     "s_load_dwordx16 %3, %5, 0x40"
                     : "=&s"(ha), "=&s"(hb), "=&s"(hc), "=&s"(hd)
                     : "s"(hp0), "s"(hp1));
    }
    int pn = p0 + 4096; if (pn > N_EDGES / 2 - 1) pn = N_EDGES / 2 - 1;
    int2   src_n = ((const int2*)ei)[pn];
    int2   dst_n = ((const int2*)(ei + N_EDGES))[pn];
    float4 ea_n  = ((const float4*)ea)[pn];

#pragma clang loop unroll(disable)
    for (int p = wslot; p < N_EDGES / 2; p += 4096) {
        f32x4 wa[8], wb[8], wc[8];
        asm volatile(                      // chunk A: i_local 0..15
            "ds_read_b128 %0, %12 offset:0\n\t"
            "ds_read_b128 %1, %12 offset:16\n\t"
            "ds_read_b128 %2, %12 offset:32\n\t"
            "ds_read_b128 %3, %12 offset:48\n\t"
            "ds_read_b128 %4, %12 offset:9216\n\t"
            "ds_read_b128 %5, %12 offset:9232\n\t"
            "ds_read_b128 %6, %12 offset:9248\n\t"
            "ds_read_b128 %7, %12 offset:9264\n\t"
            "ds_read_b128 %8, %12 offset:18432\n\t"
            "ds_read_b128 %9, %12 offset:18448\n\t"
            "ds_read_b128 %10, %12 offset:18464\n\t"
            "ds_read_b128 %11, %12 offset:18480"
            : "=&v"(wa[0]), "=&v"(wa[1]), "=&v"(wa[2]), "=&v"(wa[3]),
              "=&v"(wb[0]), "=&v"(wb[1]), "=&v"(wb[2]), "=&v"(wb[3]),
              "=&v"(wc[0]), "=&v"(wc[1]), "=&v"(wc[2]), "=&v"(wc[3])
            : "v"(laddr));
        asm volatile(                      // chunk B: i_local 16..31
            "ds_read_b128 %0, %12 offset:64\n\t"
            "ds_read_b128 %1, %12 offset:80\n\t"
            "ds_read_b128 %2, %12 offset:96\n\t"
            "ds_read_b128 %3, %12 offset:112\n\t"
            "ds_read_b128 %4, %12 offset:9280\n\t"
            "ds_read_b128 %5, %12 offset:9296\n\t"
            "ds_read_b128 %6, %12 offset:9312\n\t"
            "ds_read_b128 %7, %12 offset:9328\n\t"
            "ds_read_b128 %8, %12 offset:18496\n\t"
            "ds_read_b128 %9, %12 offset:18512\n\t"
            "ds_read_b128 %10, %12 offset:18528\n\t"
            "ds_read_b128 %11, %12 offset:18544"
            : "=&v"(wa[4]), "=&v"(wa[5]), "=&v"(wa[6]), "=&v"(wa[7]),
              "=&v"(wb[4]), "=&v"(wb[5]), "=&v"(wb[6]), "=&v"(wb[7]),
              "=&v"(wc[4]), "=&v"(wc[5]), "=&v"(wc[6]), "=&v"(wc[7])
            : "v"(laddr));

        // next-iter h pointers (SALU work fills the ds window)
        int s0n = __builtin_amdgcn_readfirstlane(src_n.x);
        int s1n = __builtin_amdgcn_readfirstlane(src_n.y);
        const float* hpn0 = h1 + (size_t)s0n * 64 + base;
        const float* hpn1 = h1 + (size_t)s1n * 64 + base;

        // single drain: weights (this iter) + h (prefetched last iter / prologue)
        asm volatile("s_waitcnt lgkmcnt(0)"
            : "+v"(wa[0]), "+v"(wa[1]), "+v"(wa[2]), "+v"(wa[3]),
              "+v"(wa[4]), "+v"(wa[5]), "+v"(wa[6]), "+v"(wa[7]),
              "+v"(wb[0]), "+v"(wb[1]), "+v"(wb[2]), "+v"(wb[3]),
              "+v"(wb[4]), "+v"(wb[5]), "+v"(wb[6]), "+v"(wb[7]),
              "+v"(wc[0]), "+v"(wc[1]), "+v"(wc[2]), "+v"(wc[3]),
              "+v"(wc[4]), "+v"(wc[5]), "+v"(wc[6]), "+v"(wc[7]),
              "+s"(ha), "+s"(hb), "+s"(hc), "+s"(hd));

        f32x2 e00 = {ea_c.x, ea_c.x}, e01 = {ea_c.y, ea_c.y};
        f32x2 e10 = {ea_c.z, ea_c.z}, e11 = {ea_c.w, ea_c.w};
        const f32x2 z2 = {0.f, 0.f};
        f32x2 acc0 = z2, acc1 = z2;
        // packed FMA half 1: i_local 0..15 (consumes ha, hc)
#pragma unroll
        for (int q = 0; q < 4; ++q) {
#pragma unroll
            for (int k = 0; k < 2; ++k) {
                f32x2 w0p = {wa[q][2 * k], wa[q][2 * k + 1]};
                f32x2 w1p = {wb[q][2 * k], wb[q][2 * k + 1]};
                f32x2 bp  = {wc[q][2 * k], wc[q][2 * k + 1]};
                f32x2 wv0 = __builtin_elementwise_max(
                    __builtin_elementwise_fma(e01, w1p,
                        __builtin_elementwise_fma(e00, w0p, bp)), z2);
                f32x2 h0p = {ha[q * 4 + 2 * k], ha[q * 4 + 2 * k + 1]};
                acc0 = __builtin_elementwise_fma(h0p, wv0, acc0);
                f32x2 wv1 = __builtin_elementwise_max(
                    __builtin_elementwise_fma(e11, w1p,
                        __builtin_elementwise_fma(e10, w0p, bp)), z2);
                f32x2 h1p = {hc[q * 4 + 2 * k], hc[q * 4 + 2 * k + 1]};
                acc1 = __builtin_elementwise_fma(h1p, wv1, acc1);
            }
        }
        // B1: ha,hc done -> issue next-iter loads into them (latency hides below)
        asm volatile("s_load_dwordx16 %0, %2, 0x0\n\t"
                     "s_load_dwordx16 %1, %3, 0x0"
                     : "=&s"(ha), "=&s"(hc) : "s"(hpn0), "s"(hpn1));
        // packed FMA half 2: i_local 16..31 (consumes hb, hd)
#pragma unroll
        for (int q = 4; q < 8; ++q) {
#pragma unroll
            for (int k = 0; k < 2; ++k) {
                f32x2 w0p = {wa[q][2 * k], wa[q][2 * k + 1]};
                f32x2 w1p = {wb[q][2 * k], wb[q][2 * k + 1]};
                f32x2 bp  = {wc[q][2 * k], wc[q][2 * k + 1]};
                f32x2 wv0 = __builtin_elementwise_max(
                    __builtin_elementwise_fma(e01, w1p,
                        __builtin_elementwise_fma(e00, w0p, bp)), z2);
                f32x2 h0p = {hb[(q - 4) * 4 + 2 * k], hb[(q - 4) * 4 + 2 * k + 1]};
                acc0 = __builtin_elementwise_fma(h0p, wv0, acc0);
                f32x2 wv1 = __builtin_elementwise_max(
                    __builtin_elementwise_fma(e11, w1p,
                        __builtin_elementwise_fma(e10, w0p, bp)), z2);
                f32x2 h1p = {hd[(q - 4) * 4 + 2 * k], hd[(q - 4) * 4 + 2 * k + 1]};
                acc1 = __builtin_elementwise_fma(h1p, wv1, acc1);
            }
        }
        // B2: hb,hd done -> issue next-iter loads
        asm volatile("s_load_dwordx16 %0, %2, 0x40\n\t"
                     "s_load_dwordx16 %1, %3, 0x40"
                     : "=&s"(hb), "=&s"(hd) : "s"(hpn0), "s"(hpn1));

        atomicAdd(&out[(size_t)dst_c.x * 64 + lane], acc0[0] + acc0[1]);
        atomicAdd(&out[(size_t)dst_c.y * 64 + lane], acc1[0] + acc1[1]);

        // rotate meta and prefetch iter t+2 (clamped in-bounds; tail junk unused)
        dst_c = dst_n; ea_c = ea_n;
        int pn2 = p + 8192; if (pn2 > N_EDGES / 2 - 1) pn2 = N_EDGES / 2 - 1;
        src_n = ((const int2*)ei)[pn2];
        dst_n = ((const int2*)(ei + N_EDGES))[pn2];
        ea_n  = ((const float4*)ea)[pn2];
    }
}

extern "C" void kernel_launch(void* const* d_in, const int* in_sizes, int n_in,
                              void* d_out, int out_size, void* d_ws, size_t ws_size,
                              hipStream_t stream) {
    const float* x     = (const float*)d_in[0];
    const int*   ei    = (const int*)d_in[1];
    const float* ea    = (const float*)d_in[2];
    const float* A1    = (const float*)d_in[3];
    const float* b1    = (const float*)d_in[4];
    const float* A2    = (const float*)d_in[5];
    const float* b2    = (const float*)d_in[6];
    const float* root1 = (const float*)d_in[7];
    const float* bias1 = (const float*)d_in[8];
    const float* root2 = (const float*)d_in[9];
    const float* bias2 = (const float*)d_in[10];
    float* out = (float*)d_out;
    float* h1  = (float*)d_ws;        // N*64 floats = 4 MB scratch

    // 1) h1 = bias1 + x @ root1   (fully initializes ws accumulator)
    k_node1<<<N_NODES * 64 / 256, 256, 0, stream>>>(x, root1, bias1, h1);
    // 2) h1 += scatter-add of layer-1 edge messages
    k_edge1<<<2048, 256, 0, stream>>>(x, ei, ea, A1, b1, h1);
    // 3) out = bias2 + h1 @ root2 (fully initializes d_out)
    k_node2<<<1024, 256, 0, stream>>>(h1, root2, bias2, out);
    // 4) out += scatter-add of layer-2 edge messages
    k_edge2<<<2048, 256, 0, stream>>>(h1, ei, ea, A2, b2, out);
}

// Round 13
// 137.793 us; speedup vs baseline: 1.1295x; 1.0024x over previous
//
#include <hip/hip_runtime.h>

#define N_NODES 16384
#define N_EDGES 65536

typedef float f32x16 __attribute__((ext_vector_type(16)));
typedef float f32x8  __attribute__((ext_vector_type(8)));
typedef float f32x4  __attribute__((ext_vector_type(4)));
typedef float f32x2  __attribute__((ext_vector_type(2)));

__device__ __forceinline__ float rfl_f(float v) {
    int i = __builtin_amdgcn_readfirstlane(__builtin_bit_cast(int, v));
    return __builtin_bit_cast(float, i);
}

// h1[n,o] = bias1[o] + sum_{i<8} x[n,i] * root1[i,o]
__global__ void k_node1(const float* __restrict__ x, const float* __restrict__ root1,
                        const float* __restrict__ bias1, float* __restrict__ h1) {
    int t = blockIdx.x * blockDim.x + threadIdx.x;   // t in [0, N*64)
    int n = t >> 6, o = t & 63;
    float acc = bias1[o];
#pragma unroll
    for (int i = 0; i < 8; ++i)
        acc = fmaf(x[n * 8 + i], root1[i * 64 + o], acc);
    h1[t] = acc;
}

// layer-1 edge kernel: wave per EDGE-PAIR; packed-f32 MLP (v_pk_fma/v_pk_max)
__global__ __launch_bounds__(256)
void k_edge1(const float* __restrict__ x, const int* __restrict__ ei,
             const float* __restrict__ ea, const float* __restrict__ A1,
             const float* __restrict__ b1, float* __restrict__ h1) {
    int lane = threadIdx.x & 63;
    f32x8 W0, W1, BB;
#pragma unroll
    for (int i = 0; i < 8; ++i) {
        W0[i] = A1[i * 64 + lane];
        W1[i] = A1[512 + i * 64 + lane];
        BB[i] = b1[i * 64 + lane];
    }
    asm volatile("" : "+v"(W0), "+v"(W1), "+v"(BB));

    int wid = blockIdx.x * (blockDim.x >> 6) + (threadIdx.x >> 6);
    int nw = gridDim.x * (blockDim.x >> 6);
#pragma clang loop unroll(disable)
    for (int p = wid; p < N_EDGES / 2; p += nw) {
        int2 srcp = ((const int2*)ei)[p];
        int2 dstp = ((const int2*)(ei + N_EDGES))[p];
        float4 eap = ((const float4*)ea)[p];
        int s0 = __builtin_amdgcn_readfirstlane(srcp.x);
        int s1 = __builtin_amdgcn_readfirstlane(srcp.y);
        int d0 = __builtin_amdgcn_readfirstlane(dstp.x);
        int d1 = __builtin_amdgcn_readfirstlane(dstp.y);
        f32x2 e00 = {rfl_f(eap.x), rfl_f(eap.x)};
        f32x2 e01 = {rfl_f(eap.y), rfl_f(eap.y)};
        f32x2 e10 = {rfl_f(eap.z), rfl_f(eap.z)};
        f32x2 e11 = {rfl_f(eap.w), rfl_f(eap.w)};
        const float* xp0 = x + (size_t)s0 * 8;
        const float* xp1 = x + (size_t)s1 * 8;
        f32x8 ha, hb;
        asm volatile("s_load_dwordx8 %0, %2, 0x0\n\t"
                     "s_load_dwordx8 %1, %3, 0x0\n\t"
                     "s_waitcnt lgkmcnt(0)"
                     : "=&s"(ha), "=&s"(hb) : "s"(xp0), "s"(xp1));
        f32x2 acc0 = {0.f, 0.f}, acc1 = {0.f, 0.f};
        const f32x2 z2 = {0.f, 0.f};
#pragma unroll
        for (int k = 0; k < 4; ++k) {
            f32x2 w0p = {W0[2 * k], W0[2 * k + 1]};
            f32x2 w1p = {W1[2 * k], W1[2 * k + 1]};
            f32x2 bp  = {BB[2 * k], BB[2 * k + 1]};
            f32x2 wv0 = __builtin_elementwise_max(
                __builtin_elementwise_fma(e01, w1p,
                    __builtin_elementwise_fma(e00, w0p, bp)), z2);
            f32x2 h0p = {ha[2 * k], ha[2 * k + 1]};
            acc0 = __builtin_elementwise_fma(h0p, wv0, acc0);
            f32x2 wv1 = __builtin_elementwise_max(
                __builtin_elementwise_fma(e11, w1p,
                    __builtin_elementwise_fma(e10, w0p, bp)), z2);
            f32x2 h1p = {hb[2 * k], hb[2 * k + 1]};
            acc1 = __builtin_elementwise_fma(h1p, wv1, acc1);
        }
        atomicAdd(&h1[(size_t)d0 * 64 + lane], acc0[0] + acc0[1]);
        atomicAdd(&h1[(size_t)d1 * 64 + lane], acc1[0] + acc1[1]);
    }
}

// out[n,o] = bias2[o] + sum_{i<64} h1[n,i] * root2[i,o]  (packed f32)
__global__ __launch_bounds__(256)
void k_node2(const float* __restrict__ h1, const float* __restrict__ root2,
             const float* __restrict__ bias2, float* __restrict__ out) {
    int lane = threadIdx.x & 63;
    f32x16 R0, R1, R2, R3;
#pragma unroll
    for (int i = 0; i < 16; ++i) {
        R0[i] = root2[(i)      * 64 + lane];
        R1[i] = root2[(16 + i) * 64 + lane];
        R2[i] = root2[(32 + i) * 64 + lane];
        R3[i] = root2[(48 + i) * 64 + lane];
    }
    asm volatile("" : "+v"(R0), "+v"(R1), "+v"(R2), "+v"(R3));
    float bias = bias2[lane];

    int wid = blockIdx.x * (blockDim.x >> 6) + (threadIdx.x >> 6);
    int nw = gridDim.x * (blockDim.x >> 6);
#pragma clang loop unroll(disable)
    for (int n = wid; n < N_NODES; n += nw) {
        int nu = __builtin_amdgcn_readfirstlane(n);   // launder for "s" constraints
        const float* hp = h1 + (size_t)nu * 64;
        f32x16 h0, h1v, h2, h3;
        asm volatile("s_load_dwordx16 %0, %4, 0x0\n\t"
                     "s_load_dwordx16 %1, %4, 0x40\n\t"
                     "s_load_dwordx16 %2, %4, 0x80\n\t"
                     "s_load_dwordx16 %3, %4, 0xc0\n\t"
                     "s_waitcnt lgkmcnt(0)"
                     : "=&s"(h0), "=&s"(h1v), "=&s"(h2), "=&s"(h3) : "s"(hp));
        f32x2 accp = {bias, 0.f};
#pragma unroll
        for (int k = 0; k < 8; ++k) {
            f32x2 hp0 = {h0[2 * k], h0[2 * k + 1]};
            f32x2 rp0 = {R0[2 * k], R0[2 * k + 1]};
            accp = __builtin_elementwise_fma(hp0, rp0, accp);
            f32x2 hp1 = {h1v[2 * k], h1v[2 * k + 1]};
            f32x2 rp1 = {R1[2 * k], R1[2 * k + 1]};
            accp = __builtin_elementwise_fma(hp1, rp1, accp);
            f32x2 hp2 = {h2[2 * k], h2[2 * k + 1]};
            f32x2 rp2 = {R2[2 * k], R2[2 * k + 1]};
            accp = __builtin_elementwise_fma(hp2, rp2, accp);
            f32x2 hp3 = {h3[2 * k], h3[2 * k + 1]};
            f32x2 rp3 = {R3[2 * k], R3[2 * k + 1]};
            accp = __builtin_elementwise_fma(hp3, rp3, accp);
        }
        out[(size_t)nu * 64 + lane] = accp[0] + accp[1];
    }
}

// layer-2 edge kernel v11: weights HOISTED into asm-opaque VGPRs (24 ds_read_b128
// executed ONCE — compiler cannot rematerialize asm outputs), software-pipelined
// h s_loads, packed-f32 inner loop. Grid 768 = 3 blocks/CU exact; 21 iters/wave.
__global__ __launch_bounds__(256, 3)
void k_edge2(const float* __restrict__ h1, const int* __restrict__ ei,
             const float* __restrict__ ea, const float* __restrict__ A2,
             const float* __restrict__ b2, float* __restrict__ out) {
    __shared__ __align__(16) float WT[3 * 64 * 36];   // 27648 B, row stride 36 dwords
    int half = blockIdx.x & 1;
    for (int j = threadIdx.x; j < 2048; j += 256) {
        int i = j >> 6, o = j & 63;
        WT[o * 36 + i]               = A2[half * 2048 + j];
        WT[64 * 36 + o * 36 + i]     = A2[4096 + half * 2048 + j];
        WT[2 * 64 * 36 + o * 36 + i] = b2[half * 2048 + j];
    }
    __syncthreads();

    int lane = threadIdx.x & 63;
    int base = __builtin_amdgcn_readfirstlane(half * 32);
    unsigned laddr = (unsigned)(uintptr_t)WT + lane * 144;

    // ---- hoisted loop-invariant weight reads (ONCE per wave) ----
    f32x4 wa[8], wb[8], wc[8];
    asm volatile(                      // chunk A: i_local 0..15
        "ds_read_b128 %0, %12 offset:0\n\t"
        "ds_read_b128 %1, %12 offset:16\n\t"
        "ds_read_b128 %2, %12 offset:32\n\t"
        "ds_read_b128 %3, %12 offset:48\n\t"
        "ds_read_b128 %4, %12 offset:9216\n\t"
        "ds_read_b128 %5, %12 offset:9232\n\t"
        "ds_read_b128 %6, %12 offset:9248\n\t"
        "ds_read_b128 %7, %12 offset:9264\n\t"
        "ds_read_b128 %8, %12 offset:18432\n\t"
        "ds_read_b128 %9, %12 offset:18448\n\t"
        "ds_read_b128 %10, %12 offset:18464\n\t"
        "ds_read_b128 %11, %12 offset:18480"
        : "=&v"(wa[0]), "=&v"(wa[1]), "=&v"(wa[2]), "=&v"(wa[3]),
          "=&v"(wb[0]), "=&v"(wb[1]), "=&v"(wb[2]), "=&v"(wb[3]),
          "=&v"(wc[0]), "=&v"(wc[1]), "=&v"(wc[2]), "=&v"(wc[3])
        : "v"(laddr));
    asm volatile(                      // chunk B: i_local 16..31
        "ds_read_b128 %0, %12 offset:64\n\t"
        "ds_read_b128 %1, %12 offset:80\n\t"
        "ds_read_b128 %2, %12 offset:96\n\t"
        "ds_read_b128 %3, %12 offset:112\n\t"
        "ds_read_b128 %4, %12 offset:9280\n\t"
        "ds_read_b128 %5, %12 offset:9296\n\t"
        "ds_read_b128 %6, %12 offset:9312\n\t"
        "ds_read_b128 %7, %12 offset:9328\n\t"
        "ds_read_b128 %8, %12 offset:18496\n\t"
        "ds_read_b128 %9, %12 offset:18512\n\t"
        "ds_read_b128 %10, %12 offset:18528\n\t"
        "ds_read_b128 %11, %12 offset:18544"
        : "=&v"(wa[4]), "=&v"(wa[5]), "=&v"(wa[6]), "=&v"(wa[7]),
          "=&v"(wb[4]), "=&v"(wb[5]), "=&v"(wb[6]), "=&v"(wb[7]),
          "=&v"(wc[4]), "=&v"(wc[5]), "=&v"(wc[6]), "=&v"(wc[7])
        : "v"(laddr));
    asm volatile("s_waitcnt lgkmcnt(0)"    // drain weight reads; pins values live
        : "+v"(wa[0]), "+v"(wa[1]), "+v"(wa[2]), "+v"(wa[3]),
          "+v"(wa[4]), "+v"(wa[5]), "+v"(wa[6]), "+v"(wa[7]),
          "+v"(wb[0]), "+v"(wb[1]), "+v"(wb[2]), "+v"(wb[3]),
          "+v"(wb[4]), "+v"(wb[5]), "+v"(wb[6]), "+v"(wb[7]),
          "+v"(wc[0]), "+v"(wc[1]), "+v"(wc[2]), "+v"(wc[3]),
          "+v"(wc[4]), "+v"(wc[5]), "+v"(wc[6]), "+v"(wc[7]));

    int g = blockIdx.x >> 1;
    int wslot = g * 4 + (threadIdx.x >> 6);            // 0..1535 per half
    const int STRIDE = 1536;                           // 768 blocks / 2 halves * 4 waves

    f32x16 ha, hb, hc, hd;           // SGPR h half-rows: edge0=(ha,hb) edge1=(hc,hd)

    // ---- prologue: meta(0), issue h(0), prefetch meta(1) ----
    int p0 = wslot;
    int2   dst_c = ((const int2*)(ei + N_EDGES))[p0];
    float4 ea_c  = ((const float4*)ea)[p0];
    {
        int2 src0 = ((const int2*)ei)[p0];
        int s0 = __builtin_amdgcn_readfirstlane(src0.x);
        int s1 = __builtin_amdgcn_readfirstlane(src0.y);
        const float* hp0 = h1 + (size_t)s0 * 64 + base;
        const float* hp1 = h1 + (size_t)s1 * 64 + base;
        asm volatile("s_load_dwordx16 %0, %4, 0x0\n\t"
                     "s_load_dwordx16 %1, %4, 0x40\n\t"
                     "s_load_dwordx16 %2, %5, 0x0\n\t"
                     "s_load_dwordx16 %3, %5, 0x40"
                     : "=&s"(ha), "=&s"(hb), "=&s"(hc), "=&s"(hd)
                     : "s"(hp0), "s"(hp1));
    }
    int pn = p0 + STRIDE; if (pn > N_EDGES / 2 - 1) pn = N_EDGES / 2 - 1;
    int2   src_n = ((const int2*)ei)[pn];
    int2   dst_n = ((const int2*)(ei + N_EDGES))[pn];
    float4 ea_n  = ((const float4*)ea)[pn];

#pragma clang loop unroll(disable)
    for (int p = wslot; p < N_EDGES / 2; p += STRIDE) {
        // next-iter h pointers
        int s0n = __builtin_amdgcn_readfirstlane(src_n.x);
        int s1n = __builtin_amdgcn_readfirstlane(src_n.y);
        const float* hpn0 = h1 + (size_t)s0n * 64 + base;
        const float* hpn1 = h1 + (size_t)s1n * 64 + base;

        // drain h s_loads (issued a full iteration ago -> nearly free)
        asm volatile("s_waitcnt lgkmcnt(0)"
            : "+s"(ha), "+s"(hb), "+s"(hc), "+s"(hd));

        f32x2 e00 = {ea_c.x, ea_c.x}, e01 = {ea_c.y, ea_c.y};
        f32x2 e10 = {ea_c.z, ea_c.z}, e11 = {ea_c.w, ea_c.w};
        const f32x2 z2 = {0.f, 0.f};
        f32x2 acc0 = z2, acc1 = z2;
        // packed FMA half 1: i_local 0..15 (consumes ha, hc)
#pragma unroll
        for (int q = 0; q < 4; ++q) {
#pragma unroll
            for (int k = 0; k < 2; ++k) {
                f32x2 w0p = {wa[q][2 * k], wa[q][2 * k + 1]};
                f32x2 w1p = {wb[q][2 * k], wb[q][2 * k + 1]};
                f32x2 bp  = {wc[q][2 * k], wc[q][2 * k + 1]};
                f32x2 wv0 = __builtin_elementwise_max(
                    __builtin_elementwise_fma(e01, w1p,
                        __builtin_elementwise_fma(e00, w0p, bp)), z2);
                f32x2 h0p = {ha[q * 4 + 2 * k], ha[q * 4 + 2 * k + 1]};
                acc0 = __builtin_elementwise_fma(h0p, wv0, acc0);
                f32x2 wv1 = __builtin_elementwise_max(
                    __builtin_elementwise_fma(e11, w1p,
                        __builtin_elementwise_fma(e10, w0p, bp)), z2);
                f32x2 h1p = {hc[q * 4 + 2 * k], hc[q * 4 + 2 * k + 1]};
                acc1 = __builtin_elementwise_fma(h1p, wv1, acc1);
            }
        }
        // B1: ha,hc consumed -> issue next-iter loads into them
        asm volatile("s_load_dwordx16 %0, %2, 0x0\n\t"
                     "s_load_dwordx16 %1, %3, 0x0"
                     : "=&s"(ha), "=&s"(hc) : "s"(hpn0), "s"(hpn1));
        // packed FMA half 2: i_local 16..31 (consumes hb, hd)
#pragma unroll
        for (int q = 4; q < 8; ++q) {
#pragma unroll
            for (int k = 0; k < 2; ++k) {
                f32x2 w0p = {wa[q][2 * k], wa[q][2 * k + 1]};
                f32x2 w1p = {wb[q][2 * k], wb[q][2 * k + 1]};
                f32x2 bp  = {wc[q][2 * k], wc[q][2 * k + 1]};
                f32x2 wv0 = __builtin_elementwise_max(
                    __builtin_elementwise_fma(e01, w1p,
                        __builtin_elementwise_fma(e00, w0p, bp)), z2);
                f32x2 h0p = {hb[(q - 4) * 4 + 2 * k], hb[(q - 4) * 4 + 2 * k + 1]};
                acc0 = __builtin_elementwise_fma(h0p, wv0, acc0);
                f32x2 wv1 = __builtin_elementwise_max(
                    __builtin_elementwise_fma(e11, w1p,
                        __builtin_elementwise_fma(e10, w0p, bp)), z2);
                f32x2 h1p = {hd[(q - 4) * 4 + 2 * k], hd[(q - 4) * 4 + 2 * k + 1]};
                acc1 = __builtin_elementwise_fma(h1p, wv1, acc1);
            }
        }
        // B2: hb,hd consumed -> issue next-iter loads
        asm volatile("s_load_dwordx16 %0, %2, 0x40\n\t"
                     "s_load_dwordx16 %1, %3, 0x40"
                     : "=&s"(hb), "=&s"(hd) : "s"(hpn0), "s"(hpn1));

        atomicAdd(&out[(size_t)dst_c.x * 64 + lane], acc0[0] + acc0[1]);
        atomicAdd(&out[(size_t)dst_c.y * 64 + lane], acc1[0] + acc1[1]);

        // rotate meta and prefetch iter t+2 (clamped in-bounds; tail junk unused)
        dst_c = dst_n; ea_c = ea_n;
        int pn2 = p + 2 * STRIDE; if (pn2 > N_EDGES / 2 - 1) pn2 = N_EDGES / 2 - 1;
        src_n = ((const int2*)ei)[pn2];
        dst_n = ((const int2*)(ei + N_EDGES))[pn2];
        ea_n  = ((const float4*)ea)[pn2];
    }
}

extern "C" void kernel_launch(void* const* d_in, const int* in_sizes, int n_in,
                              void* d_out, int out_size, void* d_ws, size_t ws_size,
                              hipStream_t stream) {
    const float* x     = (const float*)d_in[0];
    const int*   ei    = (const int*)d_in[1];
    const float* ea    = (const float*)d_in[2];
    const float* A1    = (const float*)d_in[3];
    const float* b1    = (const float*)d_in[4];
    const float* A2    = (const float*)d_in[5];
    const float* b2    = (const float*)d_in[6];
    const float* root1 = (const float*)d_in[7];
    const float* bias1 = (const float*)d_in[8];
    const float* root2 = (const float*)d_in[9];
    const float* bias2 = (const float*)d_in[10];
    float* out = (float*)d_out;
    float* h1  = (float*)d_ws;        // N*64 floats = 4 MB scratch

    // 1) h1 = bias1 + x @ root1   (fully initializes ws accumulator)
    k_node1<<<N_NODES * 64 / 256, 256, 0, stream>>>(x, root1, bias1, h1);
    // 2) h1 += scatter-add of layer-1 edge messages
    k_edge1<<<2048, 256, 0, stream>>>(x, ei, ea, A1, b1, h1);
    // 3) out = bias2 + h1 @ root2 (fully initializes d_out)
    k_node2<<<1024, 256, 0, stream>>>(h1, root2, bias2, out);
    // 4) out += scatter-add of layer-2 edge messages (768 = 3 blocks/CU exact)
    k_edge2<<<768, 256, 0, stream>>>(h1, ei, ea, A2, b2, out);
}